// Round 1
// baseline (14512.891 us; speedup 1.0000x reference)
//
#include <hip/hip_runtime.h>
#include <hip/hip_bf16.h>

typedef unsigned short u16;
typedef unsigned int   u32;
typedef __attribute__((ext_vector_type(8))) __bf16 bf16x8;
typedef __attribute__((ext_vector_type(4))) float  f32x4;

#define DT   0.1f
#define NUNF 6

__device__ __forceinline__ u16 f2bf(float f) {
    __hip_bfloat16 h = __float2bfloat16(f);   // RNE
    return __builtin_bit_cast(u16, h);
}
__device__ __forceinline__ float bf2f(u16 u) {
    return __uint_as_float(((u32)u) << 16);
}
__device__ __forceinline__ u32 pk2(float a, float b) {
    return (u32)f2bf(a) | ((u32)f2bf(b) << 16);
}

// ---------------------------------------------------------------------------
// Pack W (fp32 [1024][1536]) into MFMA-B-fragment-linear bf16 arrays:
//   Wxp[kb<16][nb<64][lane<64][i<8] = W[nb*16+(lane&15)][      kb*32+(lane>>4)*8+i]
//   Whp[kb<32][nb<64][lane<64][i<8] = W[nb*16+(lane&15)][512 + kb*32+(lane>>4)*8+i]
// So at runtime one lane's B fragment is a single contiguous 16B load.
// ---------------------------------------------------------------------------
__global__ void pack_w(const float* __restrict__ W,
                       u16* __restrict__ Wxp, u16* __restrict__ Whp)
{
    int t    = blockIdx.x * 256 + threadIdx.x;
    int lane = t & 63;
    int nb   = (t >> 6) & 63;
    int kb   = t >> 12;

    const float* src;
    u16* dst;
    if (kb < 16) {
        src = W + (size_t)(nb*16 + (lane&15))*1536 + kb*32 + ((lane>>4)<<3);
        dst = Wxp + ((size_t)(kb*64 + nb)*64 + lane)*8;
    } else {
        kb -= 16;
        if (kb >= 32) return;
        src = W + (size_t)(nb*16 + (lane&15))*1536 + 512 + kb*32 + ((lane>>4)<<3);
        dst = Whp + ((size_t)(kb*64 + nb)*64 + lane)*8;
    }
    float4 v0 = *(const float4*)(src);
    float4 v1 = *(const float4*)(src + 4);
    *(ushort4*)(dst)     = make_ushort4(f2bf(v0.x), f2bf(v0.y), f2bf(v0.z), f2bf(v0.w));
    *(ushort4*)(dst + 4) = make_ushort4(f2bf(v1.x), f2bf(v1.y), f2bf(v1.z), f2bf(v1.w));
}

// ---------------------------------------------------------------------------
// acc[2][8] += A(32 x 32*KB, swizzled bf16 in LDS) @ B(fragment-packed global)
// Wave `wave` owns output columns [wave*128, wave*128+128).
// A fragment: lane holds A[(m*16)+(lane&15)][kb*32 + (lane>>4)*8 + i]
// kb order rotated per-block to decorrelate L2 channel traffic.
// ---------------------------------------------------------------------------
template<int KB>
__device__ __forceinline__ void gemm_acc(f32x4 (&acc)[2][8], const u16* As,
                                         const u16* __restrict__ Bp,
                                         int lane, int wave, int rot)
{
    const bf16x8* Av = (const bf16x8*)As;
    const bf16x8* Bv = (const bf16x8*)Bp;
    const int la    = lane & 15;
    const int lg    = lane >> 4;
    const int swz   = la & 7;
    const int a0b   = la*128 + lg;
    const int a1b   = a0b + 16*128;
    const int bbase = wave*512 + lane;       // (wave*8)*64 + lane
#pragma unroll
    for (int kk = 0; kk < KB; kk++) {
        const int kb = (kk + rot) & (KB - 1);
        bf16x8 a0 = Av[(a0b + kb*4) ^ swz];
        bf16x8 a1 = Av[(a1b + kb*4) ^ swz];
#pragma unroll
        for (int n = 0; n < 8; n++) {
            bf16x8 b = Bv[bbase + kb*4096 + n*64];
            acc[0][n] = __builtin_amdgcn_mfma_f32_16x16x32_bf16(a0, b, acc[0][n], 0, 0, 0);
            acc[1][n] = __builtin_amdgcn_mfma_f32_16x16x32_bf16(a1, b, acc[1][n], 0, 0, 0);
        }
    }
}

// ---------------------------------------------------------------------------
// Fused kernel: block = 32 batch rows x full H=1024, 8 waves N-split (128 each).
// Computes xp = X@Wx^T + b (bf16 in LDS), then 6 RK4 unfolds fully on-chip.
// ---------------------------------------------------------------------------
__global__ __launch_bounds__(512, 2)
void fused_rk4(const float* __restrict__ X,     // [32768][512]
               const float* __restrict__ S,     // [32768][1024]
               const float* __restrict__ Bb,    // [1024]
               const u16*  __restrict__ Wxp,
               const u16*  __restrict__ Whp,
               float* __restrict__ Out)         // [32768][1024]
{
    __shared__ __align__(16) u16 Alds[32 * 1024];        // 64 KB: A-tile (swizzled)
    __shared__ __align__(16) u16 XPlds[8 * 16 * 64 * 4]; // 64 KB: xp per-lane frags

    const int tid  = threadIdx.x;
    const int lane = tid & 63;
    const int wave = tid >> 6;
    const int la   = lane & 15;
    const int lg   = lane >> 4;
    const int r0   = blockIdx.x << 5;
    const int wn0  = wave << 7;
    const int rot  = blockIdx.x & 31;

    // ---- stage inputs (cols 0..511) into A-tile as bf16 ----
    {
        const int row = tid >> 4;            // 0..31
        const int c0  = (tid & 15) << 5;     // 0..480
        const float4* src = (const float4*)(X + (size_t)(r0 + row)*512 + c0);
#pragma unroll
        for (int j = 0; j < 8; j++) {
            float4 v = src[j];
            int idx = ((row << 10) + c0 + (j << 2)) ^ ((row & 7) << 3);
            *(ushort4*)&Alds[idx] =
                make_ushort4(f2bf(v.x), f2bf(v.y), f2bf(v.z), f2bf(v.w));
        }
    }

    // ---- h init (C-fragment layout: row = m*16+lg*4+rr, col = wn0+n*16+la) ----
    float h[2][8][4];
#pragma unroll
    for (int m = 0; m < 2; m++)
#pragma unroll
        for (int n = 0; n < 8; n++) {
            const int c = wn0 + (n << 4) + la;
            const size_t rb = (size_t)(r0 + (m << 4) + (lg << 2)) * 1024 + c;
#pragma unroll
            for (int rr = 0; rr < 4; rr++) h[m][n][rr] = S[rb + (size_t)rr * 1024];
        }
    float bv[8];
#pragma unroll
    for (int n = 0; n < 8; n++) bv[n] = Bb[wn0 + (n << 4) + la];

    __syncthreads();

    // ---- xp = X@Wx^T + b ----
    f32x4 acc[2][8];
#pragma unroll
    for (int m = 0; m < 2; m++)
#pragma unroll
        for (int n = 0; n < 8; n++) acc[m][n] = (f32x4){bv[n], bv[n], bv[n], bv[n]};
    gemm_acc<16>(acc, Alds, Wxp, lane, wave, rot & 15);

#pragma unroll
    for (int m = 0; m < 2; m++)
#pragma unroll
        for (int n = 0; n < 8; n++) {
            int base = ((wave*16 + m*8 + n)*64 + lane)*4;
            *(ushort4*)&XPlds[base] = make_ushort4(
                f2bf(acc[m][n][0]), f2bf(acc[m][n][1]),
                f2bf(acc[m][n][2]), f2bf(acc[m][n][3]));
        }
    __syncthreads();   // all waves finished reading A-tile (inputs)

    auto writeA = [&](bool useK, float cs) {
#pragma unroll
        for (int m = 0; m < 2; m++)
#pragma unroll
            for (int n = 0; n < 8; n++)
#pragma unroll
                for (int rr = 0; rr < 4; rr++) {
                    float v = h[m][n][rr];
                    if (useK) v += cs * acc[m][n][rr];
                    const int r = (m << 4) + (lg << 2) + rr;
                    const int c = wn0 + (n << 4) + la;
                    Alds[((r << 10) + c) ^ ((r & 7) << 3)] = f2bf(v);
                }
    };

    writeA(false, 0.0f);   // A := h
    __syncthreads();

    u32 hsum[2][8][2];     // packed bf16 pairs (rr0|rr1, rr2|rr3)

#pragma unroll 1
    for (int u = 0; u < NUNF; u++) {
#pragma unroll 1
        for (int s = 0; s < 4; s++) {
            // acc := xp
#pragma unroll
            for (int m = 0; m < 2; m++)
#pragma unroll
                for (int n = 0; n < 8; n++) {
                    ushort4 xv = *(const ushort4*)&XPlds[((wave*16 + m*8 + n)*64 + lane)*4];
                    acc[m][n] = (f32x4){bf2f(xv.x), bf2f(xv.y), bf2f(xv.z), bf2f(xv.w)};
                }
            // acc += h_arg @ Wh^T
            gemm_acc<32>(acc, Alds, Whp, lane, wave, rot);

            const float w = (s == 1 || s == 2) ? 2.0f : 1.0f;
            // k = DT * tanh(z); hsum += w*k
#pragma unroll
            for (int m = 0; m < 2; m++)
#pragma unroll
                for (int n = 0; n < 8; n++) {
#pragma unroll
                    for (int rr = 0; rr < 4; rr++) {
                        const float z = acc[m][n][rr];
                        const float e = __expf(2.0f * z);
                        acc[m][n][rr] = DT * (1.0f - __fdividef(2.0f, e + 1.0f));
                    }
#pragma unroll
                    for (int p = 0; p < 2; p++) {
                        float hx, hy;
                        if (s == 0) { hx = 0.0f; hy = 0.0f; }
                        else {
                            u32 hv = hsum[m][n][p];
                            hx = bf2f((u16)hv);
                            hy = __uint_as_float(hv & 0xffff0000u);
                        }
                        hx += w * acc[m][n][2*p];
                        hy += w * acc[m][n][2*p + 1];
                        hsum[m][n][p] = pk2(hx, hy);
                    }
                }

            __syncthreads();   // all waves done reading A-tile
            if (s < 3) {
                writeA(true, (s < 2) ? 0.5f : 1.0f);   // A := h + c_s * k
                __syncthreads();
            } else {
                constexpr float inv6 = 1.0f / 6.0f;
#pragma unroll
                for (int m = 0; m < 2; m++)
#pragma unroll
                    for (int n = 0; n < 8; n++)
#pragma unroll
                        for (int p = 0; p < 2; p++) {
                            u32 hv = hsum[m][n][p];
                            h[m][n][2*p]     += bf2f((u16)hv) * inv6;
                            h[m][n][2*p + 1] += __uint_as_float(hv & 0xffff0000u) * inv6;
                        }
                if (u < NUNF - 1) {
                    writeA(false, 0.0f);   // A := h  (next unfold, stage 0)
                    __syncthreads();
                }
            }
        }
    }

    // ---- output ----
#pragma unroll
    for (int m = 0; m < 2; m++)
#pragma unroll
        for (int n = 0; n < 8; n++) {
            const int c = wn0 + (n << 4) + la;
            const size_t rb = (size_t)(r0 + (m << 4) + (lg << 2)) * 1024 + c;
#pragma unroll
            for (int rr = 0; rr < 4; rr++) Out[rb + (size_t)rr * 1024] = h[m][n][rr];
        }
}

// ---------------------------------------------------------------------------
extern "C" void kernel_launch(void* const* d_in, const int* in_sizes, int n_in,
                              void* d_out, int out_size, void* d_ws, size_t ws_size,
                              hipStream_t stream)
{
    const float* X  = (const float*)d_in[0];   // 32768*512
    const float* S  = (const float*)d_in[1];   // 32768*1024
    const float* W  = (const float*)d_in[2];   // 1024*1536
    const float* Bb = (const float*)d_in[3];   // 1024
    float* Out = (float*)d_out;

    u16* Wxp = (u16*)d_ws;                     // 16*64*64*8 u16 = 1 MB
    u16* Whp = Wxp + 16*64*64*8;               // 32*64*64*8 u16 = 2 MB

    pack_w<<<768, 256, 0, stream>>>(W, Wxp, Whp);
    fused_rk4<<<1024, 512, 0, stream>>>(X, S, Bb, Wxp, Whp, Out);
}

// Round 2
// 3783.614 us; speedup vs baseline: 3.8357x; 3.8357x over previous
//
#include <hip/hip_runtime.h>
#include <hip/hip_bf16.h>

typedef unsigned short u16;
typedef unsigned int   u32;
typedef __attribute__((ext_vector_type(8))) __bf16 bf16x8;
typedef __attribute__((ext_vector_type(4))) float  f32x4;

#define DT   0.1f
#define NUNF 6

__device__ __forceinline__ u16 f2bf(float f) {
    __hip_bfloat16 h = __float2bfloat16(f);   // RNE
    return __builtin_bit_cast(u16, h);
}
__device__ __forceinline__ float bf2f(u16 u) {
    return __uint_as_float(((u32)u) << 16);
}
__device__ __forceinline__ u32 pk2(float a, float b) {
    return (u32)f2bf(a) | ((u32)f2bf(b) << 16);
}

// ---------------------------------------------------------------------------
// Pack W (fp32 [1024][1536]) into MFMA-B-fragment-linear bf16 arrays:
//   Wxp[kb<16][nb<64][lane<64][i<8] = W[nb*16+(lane&15)][      kb*32+(lane>>4)*8+i]
//   Whp[kb<32][nb<64][lane<64][i<8] = W[nb*16+(lane&15)][512 + kb*32+(lane>>4)*8+i]
// One lane's B fragment = one contiguous 16B load (global_load_dwordx4).
// ---------------------------------------------------------------------------
__global__ void pack_w(const float* __restrict__ W,
                       u16* __restrict__ Wxp, u16* __restrict__ Whp)
{
    int t    = blockIdx.x * 256 + threadIdx.x;
    int lane = t & 63;
    int nb   = (t >> 6) & 63;
    int kb   = t >> 12;

    const float* src;
    u16* dst;
    if (kb < 16) {
        src = W + (size_t)(nb*16 + (lane&15))*1536 + kb*32 + ((lane>>4)<<3);
        dst = Wxp + ((size_t)(kb*64 + nb)*64 + lane)*8;
    } else {
        kb -= 16;
        if (kb >= 32) return;
        src = W + (size_t)(nb*16 + (lane&15))*1536 + 512 + kb*32 + ((lane>>4)<<3);
        dst = Whp + ((size_t)(kb*64 + nb)*64 + lane)*8;
    }
    float4 v0 = *(const float4*)(src);
    float4 v1 = *(const float4*)(src + 4);
    *(ushort4*)(dst)     = make_ushort4(f2bf(v0.x), f2bf(v0.y), f2bf(v0.z), f2bf(v0.w));
    *(ushort4*)(dst + 4) = make_ushort4(f2bf(v1.x), f2bf(v1.y), f2bf(v1.z), f2bf(v1.w));
}

// ---------------------------------------------------------------------------
// acc[8] += A(32 x 32*KB swizzled bf16 LDS, rows wm*16..+16) @ B(frag-packed)
// Wave owns output cols [wn*128, wn*128+128).
// ---------------------------------------------------------------------------
template<int KB>
__device__ __forceinline__ void gemm_acc(f32x4 (&acc)[8], const u16* As,
                                         const u16* __restrict__ Bp,
                                         int lane, int wm, int wn)
{
    const bf16x8* Av = (const bf16x8*)As;
    const bf16x8* Bv = (const bf16x8*)Bp;
    const int la    = lane & 15;
    const int lg    = lane >> 4;
    const int swz   = la & 7;
    const int a0b   = (wm*16 + la)*128 + lg;
    const int bbase = wn*512 + lane;
#pragma unroll 2
    for (int kb = 0; kb < KB; kb++) {
        bf16x8 a0 = Av[(a0b + kb*4) ^ swz];
#pragma unroll
        for (int n = 0; n < 8; n++) {
            bf16x8 b = Bv[bbase + kb*4096 + n*64];
            acc[n] = __builtin_amdgcn_mfma_f32_16x16x32_bf16(a0, b, acc[n], 0, 0, 0);
        }
    }
}

// ---------------------------------------------------------------------------
// Fused kernel: block = 32 batch rows x H=1024, 1024 thr = 16 waves (2m x 8n).
// Per thread: 8 C-fragments (32 outputs) -> acc 32 + h 32 + hsum 16 regs.
// ---------------------------------------------------------------------------
__global__ __launch_bounds__(1024, 4)
void fused_rk4(const float* __restrict__ X,     // [32768][512]
               const float* __restrict__ S,     // [32768][1024]
               const float* __restrict__ Bb,    // [1024]
               const u16*  __restrict__ Wxp,
               const u16*  __restrict__ Whp,
               float* __restrict__ Out)         // [32768][1024]
{
    __shared__ __align__(16) u16 Alds[32 * 1024];        // 64 KB (swizzled)
    __shared__ __align__(16) u16 XPlds[16 * 8 * 64 * 4]; // 64 KB xp frags

    const int tid  = threadIdx.x;
    const int lane = tid & 63;
    const int wave = tid >> 6;
    const int wm   = wave >> 3;     // 0..1  (row block)
    const int wn   = wave & 7;      // 0..7  (128-col panel)
    const int la   = lane & 15;
    const int lg   = lane >> 4;
    const int r0   = blockIdx.x << 5;

    // ---- stage inputs (cols 0..511) into A-tile as bf16 ----
    {
        const int row = tid >> 5;            // 0..31
        const int c0  = (tid & 31) << 4;     // 0..496
        const float4* src = (const float4*)(X + (size_t)(r0 + row)*512 + c0);
#pragma unroll
        for (int j = 0; j < 4; j++) {
            float4 v = src[j];
            int idx = ((row << 10) + c0 + (j << 2)) ^ ((row & 7) << 3);
            *(ushort4*)&Alds[idx] =
                make_ushort4(f2bf(v.x), f2bf(v.y), f2bf(v.z), f2bf(v.w));
        }
    }

    // ---- h init (C-frag: row = wm*16+lg*4+rr, col = wn*128+n*16+la) ----
    float h[8][4];
    const int cbase = (wn << 7) + la;
#pragma unroll
    for (int n = 0; n < 8; n++) {
        const size_t rb = (size_t)(r0 + (wm << 4) + (lg << 2)) * 1024 + cbase + (n << 4);
#pragma unroll
        for (int rr = 0; rr < 4; rr++) h[n][rr] = S[rb + (size_t)rr * 1024];
    }
    float bv[8];
#pragma unroll
    for (int n = 0; n < 8; n++) bv[n] = Bb[cbase + (n << 4)];

    __syncthreads();

    // ---- xp = X@Wx^T + b ----
    f32x4 acc[8];
#pragma unroll
    for (int n = 0; n < 8; n++) acc[n] = (f32x4){bv[n], bv[n], bv[n], bv[n]};
    gemm_acc<16>(acc, Alds, Wxp, lane, wm, wn);

#pragma unroll
    for (int n = 0; n < 8; n++) {
        int base = (((wave << 3) + n) * 64 + lane) * 4;
        *(ushort4*)&XPlds[base] = make_ushort4(
            f2bf(acc[n][0]), f2bf(acc[n][1]), f2bf(acc[n][2]), f2bf(acc[n][3]));
    }
    __syncthreads();   // also: all waves done reading A-tile (inputs)

    auto writeA = [&](bool useK, float cs) {
#pragma unroll
        for (int n = 0; n < 8; n++)
#pragma unroll
            for (int rr = 0; rr < 4; rr++) {
                float v = h[n][rr];
                if (useK) v += cs * acc[n][rr];
                const int r = (wm << 4) + (lg << 2) + rr;
                const int c = (wn << 7) + (n << 4) + la;
                Alds[((r << 10) + c) ^ ((r & 7) << 3)] = f2bf(v);
            }
    };

    writeA(false, 0.0f);   // A := h
    __syncthreads();

    u32 hsum[8][2];        // packed bf16 pairs (rr0|rr1, rr2|rr3)

#pragma unroll 1
    for (int u = 0; u < NUNF; u++) {
#pragma unroll 1
        for (int s = 0; s < 4; s++) {
            // acc := xp
#pragma unroll
            for (int n = 0; n < 8; n++) {
                ushort4 xv = *(const ushort4*)&XPlds[(((wave << 3) + n) * 64 + lane) * 4];
                acc[n] = (f32x4){bf2f(xv.x), bf2f(xv.y), bf2f(xv.z), bf2f(xv.w)};
            }
            // acc += h_arg @ Wh^T
            gemm_acc<32>(acc, Alds, Whp, lane, wm, wn);

            const float w = (s == 1 || s == 2) ? 2.0f : 1.0f;
#pragma unroll
            for (int n = 0; n < 8; n++) {
#pragma unroll
                for (int rr = 0; rr < 4; rr++) {
                    const float z = acc[n][rr];
                    const float e = __expf(2.0f * z);
                    acc[n][rr] = DT * (1.0f - __fdividef(2.0f, e + 1.0f));
                }
#pragma unroll
                for (int p = 0; p < 2; p++) {
                    float hx, hy;
                    if (s == 0) { hx = 0.0f; hy = 0.0f; }
                    else {
                        u32 hv = hsum[n][p];
                        hx = bf2f((u16)hv);
                        hy = __uint_as_float(hv & 0xffff0000u);
                    }
                    hx += w * acc[n][2*p];
                    hy += w * acc[n][2*p + 1];
                    hsum[n][p] = pk2(hx, hy);
                }
            }

            __syncthreads();   // all waves done reading A-tile
            if (s < 3) {
                writeA(true, (s < 2) ? 0.5f : 1.0f);   // A := h + c_s * k
                __syncthreads();
            } else {
                constexpr float inv6 = 1.0f / 6.0f;
#pragma unroll
                for (int n = 0; n < 8; n++)
#pragma unroll
                    for (int p = 0; p < 2; p++) {
                        u32 hv = hsum[n][p];
                        h[n][2*p]     += bf2f((u16)hv) * inv6;
                        h[n][2*p + 1] += __uint_as_float(hv & 0xffff0000u) * inv6;
                    }
                if (u < NUNF - 1) {
                    writeA(false, 0.0f);   // A := h (next unfold)
                    __syncthreads();
                }
            }
        }
    }

    // ---- output ----
#pragma unroll
    for (int n = 0; n < 8; n++) {
        const size_t rb = (size_t)(r0 + (wm << 4) + (lg << 2)) * 1024 + cbase + (n << 4);
#pragma unroll
        for (int rr = 0; rr < 4; rr++) Out[rb + (size_t)rr * 1024] = h[n][rr];
    }
}

// ---------------------------------------------------------------------------
extern "C" void kernel_launch(void* const* d_in, const int* in_sizes, int n_in,
                              void* d_out, int out_size, void* d_ws, size_t ws_size,
                              hipStream_t stream)
{
    const float* X  = (const float*)d_in[0];   // 32768*512
    const float* S  = (const float*)d_in[1];   // 32768*1024
    const float* W  = (const float*)d_in[2];   // 1024*1536
    const float* Bb = (const float*)d_in[3];   // 1024
    float* Out = (float*)d_out;

    u16* Wxp = (u16*)d_ws;                     // 1 MB
    u16* Whp = Wxp + 16*64*64*8;               // 2 MB

    pack_w<<<768, 256, 0, stream>>>(W, Wxp, Whp);
    fused_rk4<<<1024, 1024, 0, stream>>>(X, S, Bb, Wxp, Whp, Out);
}